// Round 14
// baseline (1055.083 us; speedup 1.0000x reference)
//
#include <hip/hip_runtime.h>
#include <math.h>

#define N_NODES_C 100000
#define D_FEAT 64

// interleaved bucket geometry: bucket = node & 1023, lnode = node >> 10 (0..97)
#define NB_F 1024
#define FB_SHIFT 10
#define FB_MASK (NB_F - 1)
#define LMAX 128                       // padded local-node array (actual <= 98)
#define CAP_E 3072                     // = NPROD*SUBCAP + OVF_CAP (bounds by construction)
#define COL_BITS 17                    // col < 100000 < 2^17; lnode in bits 17..23
#define COL_MASK17 0x1FFFF
#define CCS 16                         // ccursor stride (fallback path)
#define AGG_BLOCKS 512                 // fallback agg geometry (r7/r10-proven)
#define AGG_IT 8
#define NPROD 64                       // producer blocks
#define SUBCAP 40                      // slots per (bucket,producer) cell: mean 24.4 + 3.2ated
#define OVF_CAP 512                    // global overflow list capacity

// ---------------- fallback (round-1) atomic kernel ----------------
__global__ void spline_scatter_atomic(const float* __restrict__ x,
                                      const int* __restrict__ row_idx,
                                      const int* __restrict__ col_idx,
                                      const float* __restrict__ edge_attr,
                                      float* __restrict__ out,
                                      int n_edges) {
    long long t = (long long)blockIdx.x * blockDim.x + threadIdx.x;
    int e = (int)(t >> 6);
    int f = (int)(t & 63);
    if (e >= n_edges) return;
    int r = row_idx[e];
    int c = col_idx[e];
    float w = expf(-edge_attr[e]);
    atomicAdd(&out[(long long)r * D_FEAT + f], w * x[(long long)c * D_FEAT + f]);
}

// ---------------- legacy CSR-build pipeline (fallback #2) ----------------

__global__ void hist_kernel(const int* __restrict__ row_idx, int* __restrict__ counts,
                            int n_edges) {
    int e = blockIdx.x * blockDim.x + threadIdx.x;
    if (e < n_edges) atomicAdd(&counts[row_idx[e]], 1);
}

__global__ void scan_kernel(const int* __restrict__ counts, int* __restrict__ start,
                            int* __restrict__ cursor, int n) {
    __shared__ int wave_sums[16];
    __shared__ int carry_s;
    const int tid = threadIdx.x;
    const int lane = tid & 63;
    const int wid = tid >> 6;
    if (tid == 0) carry_s = 0;
    __syncthreads();
    for (int base = 0; base < n; base += 1024) {
        int i = base + tid;
        int v = (i < n) ? counts[i] : 0;
        int inc = v;
        #pragma unroll
        for (int d = 1; d < 64; d <<= 1) {
            int t = __shfl_up(inc, d, 64);
            if (lane >= d) inc += t;
        }
        if (lane == 63) wave_sums[wid] = inc;
        __syncthreads();
        if (tid == 0) {
            int s = carry_s;
            #pragma unroll
            for (int k = 0; k < 16; ++k) { int t = wave_sums[k]; wave_sums[k] = s; s += t; }
            carry_s = s;
        }
        __syncthreads();
        int excl = inc - v + wave_sums[wid];
        if (i < n) { start[i] = excl; cursor[i] = excl; }
        __syncthreads();
    }
    if (tid == 0) start[n] = carry_s;
}

__global__ void bucket_kernel(const int* __restrict__ row_idx,
                              const int* __restrict__ col_idx,
                              const float* __restrict__ edge_attr,
                              int* __restrict__ cursor,
                              int2* __restrict__ colw,
                              int n_edges) {
    int e = blockIdx.x * blockDim.x + threadIdx.x;
    if (e >= n_edges) return;
    int r = row_idx[e];
    int c = col_idx[e];
    float w = expf(-edge_attr[e]);
    int pos = atomicAdd(&cursor[r], 1);
    colw[pos] = make_int2(c, __float_as_int(w));
}

__global__ void gather_accum_kernel(const float* __restrict__ x,
                                    const int* __restrict__ start,
                                    const int2* __restrict__ colw,
                                    float* __restrict__ out,
                                    int n_nodes) {
    int node = blockIdx.x * (blockDim.x >> 6) + (threadIdx.x >> 6);
    int lane = threadIdx.x & 63;
    if (node >= n_nodes) return;
    int b = start[node];
    int e = start[node + 1];
    float acc = 0.0f;
    int j = b;
    for (; j + 3 < e; j += 4) {
        int2 c0 = colw[j], c1 = colw[j + 1], c2 = colw[j + 2], c3 = colw[j + 3];
        acc += __int_as_float(c0.y) * x[(size_t)c0.x * D_FEAT + lane];
        acc += __int_as_float(c1.y) * x[(size_t)c1.x * D_FEAT + lane];
        acc += __int_as_float(c2.y) * x[(size_t)c2.x * D_FEAT + lane];
        acc += __int_as_float(c3.y) * x[(size_t)c3.x * D_FEAT + lane];
    }
    for (; j < e; ++j) {
        int2 c0 = colw[j];
        acc += __int_as_float(c0.y) * x[(size_t)c0.x * D_FEAT + lane];
    }
    out[(size_t)node * D_FEAT + lane] = acc;
}

// ---------------- fallback #1: proven 3-dispatch fast path (r7/r10) ----------------

__global__ __launch_bounds__(512) void agg_scatter3_kernel(const int* __restrict__ row,
                                                           const int* __restrict__ col,
                                                           const float* __restrict__ attr,
                                                           int* __restrict__ ccursor,
                                                           int2* __restrict__ cw,
                                                           int n_edges, int chunk) {
    __shared__ int h[NB_F];
    __shared__ int gbase[NB_F];
    __shared__ int lcur[NB_F];
    const int tid = threadIdx.x;
    const int base = blockIdx.x * chunk;
    const int end = min(base + chunk, n_edges);
    #pragma unroll
    for (int i = tid; i < NB_F; i += 512) { h[i] = 0; lcur[i] = 0; }
    __syncthreads();
    int rc[AGG_IT];
    #pragma unroll
    for (int k = 0; k < AGG_IT; ++k) {
        int e = base + k * 512 + tid;
        rc[k] = (e < end) ? row[e] : -1;
        if (rc[k] >= 0) atomicAdd(&h[rc[k] & FB_MASK], 1);
    }
    __syncthreads();
    #pragma unroll
    for (int i = tid; i < NB_F; i += 512) {
        int c = h[i];
        gbase[i] = c ? atomicAdd(&ccursor[i * CCS], c) : 0;
    }
    __syncthreads();
    #pragma unroll
    for (int k = 0; k < AGG_IT; ++k) {
        int e = base + k * 512 + tid;
        int r = rc[k];
        if (r >= 0) {
            int b = r & FB_MASK;
            float w = expf(-attr[e]);
            int rel = gbase[b] + atomicAdd(&lcur[b], 1);
            if (rel < CAP_E)
                cw[(size_t)b * CAP_E + rel] =
                    make_int2(col[e] | ((r >> FB_SHIFT) << COL_BITS), __float_as_int(w));
        }
    }
}

__global__ __launch_bounds__(512, 8) void bucket_fused5_kernel(const float* __restrict__ x,
                                                               const int2* __restrict__ cw,
                                                               const int* __restrict__ ccursor,
                                                               float* __restrict__ out,
                                                               int n_nodes) {
    __shared__ int2 sorted[CAP_E];
    __shared__ int lhist[LMAX];
    __shared__ int lbase[LMAX];
    __shared__ int lcur[LMAX];
    __shared__ int wsum[2];
    const int b = blockIdx.x;
    const int tid = threadIdx.x;
    const int lane = tid & 63;
    const int wid = tid >> 6;
    const size_t beg = (size_t)b * CAP_E;
    int n = ccursor[b * CCS];
    if (n > CAP_E) n = CAP_E;
    if (tid < LMAX) lhist[tid] = 0;
    __syncthreads();
    int2 my[CAP_E / 512];
    #pragma unroll
    for (int k = 0; k < CAP_E / 512; ++k) {
        int i = tid + k * 512;
        if (i < n) {
            int2 d = cw[beg + i];
            my[k] = d;
            atomicAdd(&lhist[d.x >> COL_BITS], 1);
        }
    }
    __syncthreads();
    int v = 0, inc = 0;
    if (tid < LMAX) {
        v = lhist[tid];
        inc = v;
        #pragma unroll
        for (int d = 1; d < 64; d <<= 1) {
            int t = __shfl_up(inc, d, 64);
            if (lane >= d) inc += t;
        }
        if (lane == 63) wsum[wid] = inc;
    }
    __syncthreads();
    if (tid == 0) { int s = 0; for (int k = 0; k < 2; ++k) { int t = wsum[k]; wsum[k] = s; s += t; } }
    __syncthreads();
    if (tid < LMAX) { int excl = inc - v + wsum[wid]; lbase[tid] = excl; lcur[tid] = excl; }
    __syncthreads();
    #pragma unroll
    for (int k = 0; k < CAP_E / 512; ++k) {
        int i = tid + k * 512;
        if (i < n) {
            int2 d = my[k];
            int p = atomicAdd(&lcur[d.x >> COL_BITS], 1);
            sorted[p] = make_int2(d.x & COL_MASK17, d.y);
        }
    }
    __syncthreads();
    const int sl = tid & 15;
    const int grp = tid >> 4;
    const float* xb = x + (sl << 2);
    #pragma unroll
    for (int t2 = 0; t2 < 4; ++t2) {
        int ln = t2 * 32 + grp;
        int node = b + (ln << FB_SHIFT);
        int s = lbase[ln];
        int e2 = (ln + 1 < LMAX) ? lbase[ln + 1] : n;
        float4 acc = make_float4(0.f, 0.f, 0.f, 0.f);
        int j = s;
        for (; j + 8 <= e2; j += 8) {
            #pragma unroll
            for (int k = 0; k < 8; ++k) {
                int2 d = sorted[j + k];
                const float4 xv = *(const float4*)(xb + ((size_t)d.x << 6));
                float w = __int_as_float(d.y);
                acc.x += w * xv.x; acc.y += w * xv.y; acc.z += w * xv.z; acc.w += w * xv.w;
            }
        }
        #pragma unroll
        for (int k = 0; k < 7; ++k) {
            if (j + k < e2) {
                int2 d = sorted[j + k];
                const float4 xv = *(const float4*)(xb + ((size_t)d.x << 6));
                float w = __int_as_float(d.y);
                acc.x += w * xv.x; acc.y += w * xv.y; acc.z += w * xv.z; acc.w += w * xv.w;
            }
        }
        if (node < n_nodes)
            *(float4*)(out + ((size_t)node << 6) + (sl << 2)) = acc;
    }
}

// ---------------- primary: single producer/consumer kernel ----------------
// Normal launch (NOT cooperative — r11 lesson: coop launch makes all memory
// uncached-slow). Cross-XCD data goes through NONTEMPORAL stores/loads
// (bypasses the non-coherent per-XCD L2s; L3 is the chip-level coherence
// point), and the done/ovf flags use device-scope acquire/release atomics.
// Producers = blocks 0..NPROD-1 (lowest ids, dispatched first; all 1024
// blocks are co-resident anyway at 30.7 KB LDS). Each producer appends into
// exclusively-owned (bucket,producer) cells -> no global atomics, no hist
// pass, single-writer lines. Rare cell overflow (subcap = mean+3.2sigma) goes
// to a tiny global list consumed by all blocks; bounds: NPROD*SUBCAP+OVF_CAP
// == CAP_E exactly.
__global__ __launch_bounds__(512, 8) void mega_pipe_kernel(const float* __restrict__ x,
                                                           const int* __restrict__ row,
                                                           const int* __restrict__ col,
                                                           const float* __restrict__ attr,
                                                           long long* __restrict__ cw2,
                                                           int* __restrict__ cntT,
                                                           int4* __restrict__ ovf,
                                                           int* __restrict__ flags,
                                                           float* __restrict__ out,
                                                           int n_edges, int n_nodes,
                                                           int chunk) {
    __shared__ int lcurP[NB_F];           // 4 KB (producer cursors)
    __shared__ int2 sorted[CAP_E];        // 24 KB
    __shared__ int lhist[LMAX];
    __shared__ int lbase[LMAX];
    __shared__ int lcur[LMAX];
    __shared__ int pcnt[NPROD];
    __shared__ int ppre[NPROD];
    __shared__ int wsum[2];
    __shared__ int sh_ptot;
    __shared__ int sh_novfg;
    __shared__ int sh_novfb;
    const int tid = threadIdx.x;
    const int bid = blockIdx.x;
    const int lane = tid & 63;
    const int wid = tid >> 6;
    int* done = flags;                    // flags[0]=done, flags[16]=ovf_cnt
    int* ovf_cnt = flags + 16;

    // ---- produce (blocks 0..NPROD-1) ----
    if (bid < NPROD) {
        for (int i = tid; i < NB_F; i += 512) lcurP[i] = 0;
        __syncthreads();
        const int base = bid * chunk;
        const int end = min(base + chunk, n_edges);
        for (int e = base + tid; e < end; e += 512) {
            int r = row[e];
            int b = r & FB_MASK;
            int pos = atomicAdd(&lcurP[b], 1);            // native LDS int atomic
            float w = expf(-attr[e]);
            int lo = col[e] | ((r >> FB_SHIFT) << COL_BITS);
            if (pos < SUBCAP) {
                long long pv = ((long long)__float_as_int(w) << 32) | (unsigned int)lo;
                __builtin_nontemporal_store(pv,
                    cw2 + ((size_t)b * NPROD + bid) * SUBCAP + pos);
            } else {
                int op = __hip_atomic_fetch_add(ovf_cnt, 1, __ATOMIC_RELAXED,
                                                __HIP_MEMORY_SCOPE_AGENT);
                if (op < OVF_CAP)
                    ovf[op] = make_int4(r, col[e], __float_as_int(w), 0);
            }
        }
        __syncthreads();
        for (int i = tid; i < NB_F; i += 512)
            __builtin_nontemporal_store(min(lcurP[i], SUBCAP), cntT + (size_t)bid * NB_F + i);
        __syncthreads();   // s_waitcnt vmcnt(0) before barrier: all stores drained
        if (tid == 0) {
            __threadfence();                              // release: wb this XCD's L2 (ovf)
            __hip_atomic_fetch_add(done, 1, __ATOMIC_RELEASE, __HIP_MEMORY_SCOPE_AGENT);
        }
    }

    // ---- wait for all producers ----
    if (tid == 0) {
        long long guard = 0;
        while (__hip_atomic_load(done, __ATOMIC_ACQUIRE, __HIP_MEMORY_SCOPE_AGENT) < NPROD) {
            __builtin_amdgcn_s_sleep(8);
            if (++guard > 4000000LL) break;   // safety valve; never triggers
        }
        int g = __hip_atomic_load(ovf_cnt, __ATOMIC_ACQUIRE, __HIP_MEMORY_SCOPE_AGENT);
        sh_novfg = min(g, OVF_CAP);
        sh_novfb = 0;
        __threadfence();                      // acquire: invalidate stale lines (ovf)
    }
    __syncthreads();
    const int novfg = sh_novfg;

    // ---- consume bucket bid ----
    const int b = bid;
    if (tid < NPROD) { pcnt[tid] = 0; ppre[tid] = 0; }
    if (tid < LMAX) lhist[tid] = 0;
    __syncthreads();
    if (tid < NPROD) {                        // NPROD=64: all in wave 0
        int c = __builtin_nontemporal_load(cntT + (size_t)tid * NB_F + b);
        if (c > SUBCAP) c = SUBCAP;
        pcnt[tid] = c;
        int inc = c;
        #pragma unroll
        for (int d = 1; d < 64; d <<= 1) {
            int t = __shfl_up(inc, d, 64);
            if (lane >= d) inc += t;
        }
        ppre[tid] = inc - c;
        if (tid == NPROD - 1) sh_ptot = inc;
    }
    __syncthreads();

    // pass A: lnode histogram over this bucket's cells (+ overflow)
    for (int k = wid; k < NPROD; k += 8) {
        int c = pcnt[k];
        const long long* cell = cw2 + ((size_t)b * NPROD + k) * SUBCAP;
        for (int i = lane; i < c; i += 64) {
            long long pv = __builtin_nontemporal_load(cell + i);
            int lo = (int)pv;
            atomicAdd(&lhist[(lo & 0xFFFFFF) >> COL_BITS], 1);
        }
    }
    for (int i = tid; i < novfg; i += 512) {
        int4 o = ovf[i];
        if ((o.x & FB_MASK) == b) {
            atomicAdd(&lhist[o.x >> FB_SHIFT], 1);
            atomicAdd(&sh_novfb, 1);
        }
    }
    __syncthreads();
    // scan lhist[0..127]
    int v = 0, inc2 = 0;
    if (tid < LMAX) {
        v = lhist[tid];
        inc2 = v;
        #pragma unroll
        for (int d = 1; d < 64; d <<= 1) {
            int t = __shfl_up(inc2, d, 64);
            if (lane >= d) inc2 += t;
        }
        if (lane == 63) wsum[wid] = inc2;
    }
    __syncthreads();
    if (tid == 0) { int s = 0; for (int k = 0; k < 2; ++k) { int t = wsum[k]; wsum[k] = s; s += t; } }
    __syncthreads();
    if (tid < LMAX) { int excl = inc2 - v + wsum[wid]; lbase[tid] = excl; lcur[tid] = excl; }
    __syncthreads();
    const int n = sh_ptot + sh_novfb;         // <= NPROD*SUBCAP + OVF_CAP == CAP_E

    // pass B: place into lnode-sorted LDS order
    for (int k = wid; k < NPROD; k += 8) {
        int c = pcnt[k];
        const long long* cell = cw2 + ((size_t)b * NPROD + k) * SUBCAP;
        for (int i = lane; i < c; i += 64) {
            long long pv = __builtin_nontemporal_load(cell + i);
            int lo = (int)pv;
            int hi = (int)(pv >> 32);
            int p = atomicAdd(&lcur[(lo & 0xFFFFFF) >> COL_BITS], 1);
            sorted[p] = make_int2(lo & COL_MASK17, hi);
        }
    }
    for (int i = tid; i < novfg; i += 512) {
        int4 o = ovf[i];
        if ((o.x & FB_MASK) == b) {
            int p = atomicAdd(&lcur[o.x >> FB_SHIFT], 1);
            sorted[p] = make_int2(o.y, o.z);
        }
    }
    __syncthreads();

    // gather (r9-proven, unchanged)
    const int sl = tid & 15;
    const int grp = tid >> 4;
    const float* xb = x + (sl << 2);
    #pragma unroll
    for (int t2 = 0; t2 < 4; ++t2) {
        int ln = t2 * 32 + grp;
        int node = b + (ln << FB_SHIFT);
        int s = lbase[ln];
        int e2 = (ln + 1 < LMAX) ? lbase[ln + 1] : n;
        float4 acc = make_float4(0.f, 0.f, 0.f, 0.f);
        int j = s;
        for (; j + 8 <= e2; j += 8) {
            #pragma unroll
            for (int k = 0; k < 8; ++k) {
                int2 d = sorted[j + k];
                const float4 xv = *(const float4*)(xb + ((size_t)d.x << 6));
                float w = __int_as_float(d.y);
                acc.x += w * xv.x; acc.y += w * xv.y; acc.z += w * xv.z; acc.w += w * xv.w;
            }
        }
        #pragma unroll
        for (int k = 0; k < 7; ++k) {
            if (j + k < e2) {
                int2 d = sorted[j + k];
                const float4 xv = *(const float4*)(xb + ((size_t)d.x << 6));
                float w = __int_as_float(d.y);
                acc.x += w * xv.x; acc.y += w * xv.y; acc.z += w * xv.z; acc.w += w * xv.w;
            }
        }
        if (node < n_nodes)
            *(float4*)(out + ((size_t)node << 6) + (sl << 2)) = acc;
    }
}

extern "C" void kernel_launch(void* const* d_in, const int* in_sizes, int n_in,
                              void* d_out, int out_size, void* d_ws, size_t ws_size,
                              hipStream_t stream) {
    const float* x    = (const float*)d_in[0];
    const int*   eidx = (const int*)d_in[1];   // flat (2, E): [row | col]
    const float* attr = (const float*)d_in[2];
    float*       out  = (float*)d_out;

    const int n_edges = in_sizes[2];
    const int n_nodes = N_NODES_C;
    const int* row = eidx;
    const int* col = eidx + n_edges;

    // ---------- primary: single-kernel producer/consumer ----------
    // cw2[NB_F][NPROD][SUBCAP] ll (20.97MB) + cntT[NPROD][NB_F] (256KB)
    // + ovf int4[OVF_CAP] (8KB) + flags (128B)  ~= 21.24 MB
    {
        size_t off_cw2   = 0;
        size_t off_cnt   = off_cw2 + (size_t)NB_F * NPROD * SUBCAP * sizeof(long long);
        size_t off_ovf   = off_cnt + (size_t)NPROD * NB_F * sizeof(int);
        size_t off_flags = (off_ovf + (size_t)OVF_CAP * sizeof(int4) + 63) & ~(size_t)63;
        size_t need      = off_flags + 128;
        const int chunk  = (n_edges + NPROD - 1) / NPROD;          // 25000
        const double mean = (double)chunk / (double)NB_F;          // 24.41
        // gate check (numeric, r13 lesson): 24.41 + 3*4.94 = 39.2 <= 40 -> PASSES
        bool ok = (mean + 3.0 * sqrt(mean)) <= (double)SUBCAP;
        ok = ok && (n_nodes <= NB_F * LMAX) && (ws_size >= need);
        if (ok) {
            char* ws = (char*)d_ws;
            long long* cw2 = (long long*)(ws + off_cw2);
            int*  cntT  = (int*)(ws + off_cnt);
            int4* ovf   = (int4*)(ws + off_ovf);
            int*  flags = (int*)(ws + off_flags);

            hipMemsetAsync(flags, 0, 128, stream);
            mega_pipe_kernel<<<NB_F, 512, 0, stream>>>(x, row, col, attr, cw2, cntT, ovf,
                                                       flags, out, n_edges, n_nodes, chunk);
            return;
        }
    }

    // ---------- fallback #1: proven 3-dispatch fast path ----------
    {
        size_t off_cw   = 0;
        size_t off_ccur = off_cw + (size_t)NB_F * CAP_E * sizeof(int2);
        size_t need     = off_ccur + (size_t)NB_F * CCS * sizeof(int);
        const int chunk = (n_edges + AGG_BLOCKS - 1) / AGG_BLOCKS;
        const double mean_fill = (double)n_edges / (double)NB_F;
        bool ok = (mean_fill + 12.0 * sqrt(mean_fill) + 128.0) <= (double)CAP_E;
        ok = ok && (chunk <= 512 * AGG_IT) && (n_nodes <= NB_F * LMAX);
        if (ws_size >= need && ok) {
            char* ws = (char*)d_ws;
            int2* cw      = (int2*)(ws + off_cw);
            int*  ccursor = (int*)(ws + off_ccur);
            hipMemsetAsync(ccursor, 0, (size_t)NB_F * CCS * sizeof(int), stream);
            agg_scatter3_kernel<<<AGG_BLOCKS, 512, 0, stream>>>(row, col, attr, ccursor,
                                                                cw, n_edges, chunk);
            bucket_fused5_kernel<<<NB_F, 512, 0, stream>>>(x, cw, ccursor, out, n_nodes);
            return;
        }
    }

    // ---------- legacy CSR layout (fallback #2) ----------
    size_t l_off_colw   = 0;
    size_t l_off_counts = l_off_colw + (size_t)n_edges * sizeof(int2);
    size_t l_off_start  = l_off_counts + (size_t)n_nodes * sizeof(int);
    size_t l_off_cursor = l_off_start + (size_t)(n_nodes + 1) * sizeof(int);
    size_t ws_needed_old = l_off_cursor + (size_t)n_nodes * sizeof(int);

    if (ws_size >= ws_needed_old) {
        char* ws = (char*)d_ws;
        int2* colw   = (int2*)(ws + l_off_colw);
        int*  counts = (int*)(ws + l_off_counts);
        int*  start  = (int*)(ws + l_off_start);
        int*  cursor = (int*)(ws + l_off_cursor);

        hipMemsetAsync(counts, 0, (size_t)n_nodes * sizeof(int), stream);

        const int eb = (n_edges + 255) / 256;
        hist_kernel<<<eb, 256, 0, stream>>>(row, counts, n_edges);
        scan_kernel<<<1, 1024, 0, stream>>>(counts, start, cursor, n_nodes);
        bucket_kernel<<<eb, 256, 0, stream>>>(row, col, attr, cursor, colw, n_edges);

        const int waves_per_block = 4;
        const int nb = (n_nodes + waves_per_block - 1) / waves_per_block;
        gather_accum_kernel<<<nb, 256, 0, stream>>>(x, start, colw, out, n_nodes);
        return;
    }

    // ---------- last resort: atomic kernel ----------
    hipMemsetAsync(out, 0, (size_t)out_size * sizeof(float), stream);
    const long long total = (long long)n_edges * 64;
    const int blocks = (int)((total + 255) / 256);
    spline_scatter_atomic<<<blocks, 256, 0, stream>>>(x, row, col, attr, out, n_edges);
}